// Round 1
// 874.616 us; speedup vs baseline: 1.1144x; 1.1144x over previous
//
#include <hip/hip_runtime.h>
#include <math.h>

#define NN 8192
#define NFEAT 1024
#define NHID 256
#define NCLS 16
#define ELLW 128

typedef unsigned short u16;
typedef __bf16 bf16x8 __attribute__((ext_vector_type(8)));
typedef float f32x4 __attribute__((ext_vector_type(4)));

__device__ __forceinline__ float u2f(u16 h) {
    union { unsigned int u; float f; } x; x.u = ((unsigned int)h) << 16; return x.f;
}
__device__ __forceinline__ u16 f2b(float f) {
    union { float f; unsigned int u; } x; x.f = f;
    unsigned int r = x.u + 0x7FFFu + ((x.u >> 16) & 1u);
    return (u16)(r >> 16);
}
__device__ __forceinline__ float softplusf(float x) {
    return (x > 20.f) ? x : log1pf(expf(x));
}
__device__ __forceinline__ float eluf(float x) {
    return x > 0.f ? x : expm1f(x);
}
// dual-dtype scalar load: F=1 -> fp32 buffer, F=0 -> bf16 buffer
__device__ __forceinline__ float ldsc(const void* p, int k, int F) {
    return F ? ((const float*)p)[k] : u2f(((const u16*)p)[k]);
}

// ---------- 0. dtype detection + calib zero ----------
__global__ __launch_bounds__(64) void k_detect(const unsigned int* __restrict__ x32,
                                               int* __restrict__ flag,
                                               float* __restrict__ calib)
{
    const int t = threadIdx.x;
    unsigned int maxe = 0; int nz = 0;
    #pragma unroll
    for (int q = 0; q < 4; q++) {
        unsigned int w = x32[t * 4 + q];
        unsigned int e = (w >> 7) & 0xFFu;       // exponent field of low half as bf16
        maxe = maxe > e ? maxe : e;
        nz += ((w & 0xFFFFu) == 0u) ? 1 : 0;
    }
    #pragma unroll
    for (int off = 32; off >= 1; off >>= 1) {
        unsigned int me = __shfl_xor(maxe, off);
        maxe = maxe > me ? maxe : me;
        nz += __shfl_xor(nz, off);
    }
    if (t == 0) {
        flag[0] = (maxe > 0x90u || nz > 128) ? 1 : 0;
        calib[0] = 0.f;
    }
}

// ---------- 1. sparsity extraction: adj [NN][NN] (fp32 or bf16) -> ELL ----------
__global__ __launch_bounds__(256) void k_extract(
    const void* __restrict__ adjp, u16* __restrict__ eidx, u16* __restrict__ eadjh,
    u16* __restrict__ edegh, int* __restrict__ cnt, const int* __restrict__ dflag)
{
    const int F = dflag[0];
    const int i = blockIdx.x;
    const int t = threadIdx.x;
    __shared__ int scnt;
    if (t == 0) scnt = 0;
    float aii = F ? ((const float*)adjp)[(size_t)i * NN + i]
                  : u2f(((const u16*)adjp)[(size_t)i * NN + i]);
    __syncthreads();
    for (int b = 0; b < 4; b++) {
        int j0 = b * 2048 + t * 8;
        float va[8];
        if (F) {
            const float* g = (const float*)adjp + (size_t)i * NN + j0;
            float4 f0 = ((const float4*)g)[0];
            float4 f1 = ((const float4*)g)[1];
            va[0] = f0.x; va[1] = f0.y; va[2] = f0.z; va[3] = f0.w;
            va[4] = f1.x; va[5] = f1.y; va[6] = f1.z; va[7] = f1.w;
        } else {
            const u16* g = (const u16*)adjp + (size_t)i * NN + j0;
            uint4 v = *(const uint4*)g;
            unsigned int ws4[4] = { v.x, v.y, v.z, v.w };
            #pragma unroll
            for (int q = 0; q < 4; q++) {
                va[q * 2]     = u2f((u16)(ws4[q] & 0xFFFFu));
                va[q * 2 + 1] = u2f((u16)(ws4[q] >> 16));
            }
        }
        #pragma unroll
        for (int q = 0; q < 8; q++) {
            int j = j0 + q;
            if (va[q] != 0.f && j != i) {
                int p = atomicAdd(&scnt, 1);
                if (p < ELLW) {
                    eidx[(size_t)i * ELLW + p] = (u16)j;
                    eadjh[(size_t)i * ELLW + p] = f2b(va[q]);
                    edegh[(size_t)i * ELLW + p] = f2b(aii / fmaxf(va[q], 1e-9f) - 1.0f);
                }
            }
        }
    }
    __syncthreads();
    if (t == 0) cnt[i] = (scnt < ELLW) ? scnt : ELLW;
}

// ---------- 2. MFMA GEMM body: C[m0..][n0..] = A @ B^T (+bias)(elu) ----------
// fp32 operands are hi/lo bf16 split in-staging (3 MFMAs: hh + lh + hl).
// flags: bit0 = add bias, bit1 = elu
__device__ __forceinline__ void gemm_body(
    const void* __restrict__ Ap, bool af, const void* __restrict__ Bp, bool bf,
    const void* __restrict__ biasp, float* __restrict__ C,
    int m0, int n0, int N, int K, int flags, int F)
{
    const int LDT = 40;  // 32 + 8 pad
    __shared__ __align__(16) u16 Ah[128 * 40];
    __shared__ __align__(16) u16 Al[128 * 40];
    __shared__ __align__(16) u16 Bh[128 * 40];
    __shared__ __align__(16) u16 Bl[128 * 40];
    const int t = threadIdx.x;
    const int lane = t & 63, wv = t >> 6;
    const int quad = lane >> 4, lr = lane & 15;
    const int wr0 = (wv >> 1) * 64, wc0 = (wv & 1) * 64;

    f32x4 acc[4][4];
    #pragma unroll
    for (int a = 0; a < 4; a++)
        #pragma unroll
        for (int b = 0; b < 4; b++) acc[a][b] = f32x4{0.f, 0.f, 0.f, 0.f};

    const int sr = t >> 1;
    const int sk = (t & 1) * 16;

    for (int kt = 0; kt < K; kt += 32) {
        // ---- stage A ----
        if (af) {
            const float* g = (const float*)Ap + (size_t)(m0 + sr) * K + kt + sk;
            float4 f0 = ((const float4*)g)[0];
            float4 f1 = ((const float4*)g)[1];
            float4 f2 = ((const float4*)g)[2];
            float4 f3 = ((const float4*)g)[3];
            float va[16] = { f0.x, f0.y, f0.z, f0.w, f1.x, f1.y, f1.z, f1.w,
                             f2.x, f2.y, f2.z, f2.w, f3.x, f3.y, f3.z, f3.w };
            #pragma unroll
            for (int q = 0; q < 16; q++) {
                u16 h = f2b(va[q]);
                Ah[sr * LDT + sk + q] = h;
                Al[sr * LDT + sk + q] = f2b(va[q] - u2f(h));
            }
        } else {
            const u16* g = (const u16*)Ap + (size_t)(m0 + sr) * K + kt + sk;
            *(uint4*)&Ah[sr * LDT + sk]     = ((const uint4*)g)[0];
            *(uint4*)&Ah[sr * LDT + sk + 8] = ((const uint4*)g)[1];
        }
        // ---- stage B ----
        if (bf) {
            const float* g = (const float*)Bp + (size_t)(n0 + sr) * K + kt + sk;
            float4 f0 = ((const float4*)g)[0];
            float4 f1 = ((const float4*)g)[1];
            float4 f2 = ((const float4*)g)[2];
            float4 f3 = ((const float4*)g)[3];
            float vb[16] = { f0.x, f0.y, f0.z, f0.w, f1.x, f1.y, f1.z, f1.w,
                             f2.x, f2.y, f2.z, f2.w, f3.x, f3.y, f3.z, f3.w };
            #pragma unroll
            for (int q = 0; q < 16; q++) {
                u16 h = f2b(vb[q]);
                Bh[sr * LDT + sk + q] = h;
                Bl[sr * LDT + sk + q] = f2b(vb[q] - u2f(h));
            }
        } else {
            const u16* g = (const u16*)Bp + (size_t)(n0 + sr) * K + kt + sk;
            *(uint4*)&Bh[sr * LDT + sk]     = ((const uint4*)g)[0];
            *(uint4*)&Bh[sr * LDT + sk + 8] = ((const uint4*)g)[1];
        }
        __syncthreads();
        bf16x8 ah[4], bh[4];
        #pragma unroll
        for (int mt = 0; mt < 4; mt++)
            ah[mt] = *(const bf16x8*)&Ah[(wr0 + mt * 16 + lr) * LDT + quad * 8];
        #pragma unroll
        for (int nt = 0; nt < 4; nt++)
            bh[nt] = *(const bf16x8*)&Bh[(wc0 + nt * 16 + lr) * LDT + quad * 8];
        #pragma unroll
        for (int mt = 0; mt < 4; mt++)
            #pragma unroll
            for (int nt = 0; nt < 4; nt++)
                acc[mt][nt] = __builtin_amdgcn_mfma_f32_16x16x32_bf16(ah[mt], bh[nt], acc[mt][nt], 0, 0, 0);
        if (af) {
            bf16x8 al[4];
            #pragma unroll
            for (int mt = 0; mt < 4; mt++)
                al[mt] = *(const bf16x8*)&Al[(wr0 + mt * 16 + lr) * LDT + quad * 8];
            #pragma unroll
            for (int mt = 0; mt < 4; mt++)
                #pragma unroll
                for (int nt = 0; nt < 4; nt++)
                    acc[mt][nt] = __builtin_amdgcn_mfma_f32_16x16x32_bf16(al[mt], bh[nt], acc[mt][nt], 0, 0, 0);
        }
        if (bf) {
            bf16x8 bl[4];
            #pragma unroll
            for (int nt = 0; nt < 4; nt++)
                bl[nt] = *(const bf16x8*)&Bl[(wc0 + nt * 16 + lr) * LDT + quad * 8];
            #pragma unroll
            for (int mt = 0; mt < 4; mt++)
                #pragma unroll
                for (int nt = 0; nt < 4; nt++)
                    acc[mt][nt] = __builtin_amdgcn_mfma_f32_16x16x32_bf16(ah[mt], bl[nt], acc[mt][nt], 0, 0, 0);
        }
        __syncthreads();
    }

    #pragma unroll
    for (int mt = 0; mt < 4; mt++) {
        #pragma unroll
        for (int nt = 0; nt < 4; nt++) {
            int col = n0 + wc0 + nt * 16 + lr;
            float bsv = (flags & 1) ? ldsc(biasp, col, F) : 0.f;
            #pragma unroll
            for (int r = 0; r < 4; r++) {
                int rowi = m0 + wr0 + mt * 16 + quad * 4 + r;
                float v = acc[mt][nt][r] + bsv;
                if (flags & 2) v = eluf(v);
                C[(size_t)rowi * N + col] = v;
            }
        }
    }
}

__global__ __launch_bounds__(256) void k_gemm(
    const void* __restrict__ Ap, int a_f32, const void* __restrict__ Bp,
    const void* __restrict__ biasp, float* __restrict__ C,
    int N, int K, int flags, const int* __restrict__ dflag)
{
    const int F = dflag[0];
    gemm_body(Ap, (a_f32 != 0) || (F != 0), Bp, F != 0, biasp, C,
              blockIdx.x * 128, blockIdx.y * 128, N, K, flags, F);
}

// fused dual-B GEMM on x: y<2 -> prev=elu(x@fcnW^T+fcnb), y>=2 -> Wh=x@W0^T+b0
// 256 blocks -> full-GPU occupancy; x read twice but second pass is LLC-hot.
__global__ __launch_bounds__(256) void k_gemm_x(
    const void* __restrict__ x,
    const void* __restrict__ fcnW, const void* __restrict__ fcnb,
    const void* __restrict__ W0, const void* __restrict__ b0,
    float* __restrict__ prev, float* __restrict__ Wh,
    const int* __restrict__ dflag)
{
    const int F = dflag[0];
    const int sel = blockIdx.y >> 1;
    const int n0 = (blockIdx.y & 1) * 128;
    const void* B = sel ? W0 : fcnW;
    const void* bs = sel ? b0 : fcnb;
    float* C = sel ? Wh : prev;
    const int flags = sel ? 1 : 3;
    gemm_body(x, F != 0, B, F != 0, bs, C,
              blockIdx.x * 128, n0, NHID, NFEAT, flags, F);
}

// ---------- 3. row norms of Wh (fp32 [NN][NHID]) ----------
__global__ __launch_bounds__(256) void k_rownorm(const float* __restrict__ Wh, float* __restrict__ nrm)
{
    const int t = threadIdx.x;
    const int lane = t & 63, wv = t >> 6;
    const int row = blockIdx.x * 4 + wv;
    float4 v = *(const float4*)&Wh[(size_t)row * NHID + lane * 4];
    float p = v.x * v.x + v.y * v.y + v.z * v.z + v.w * v.w;
    #pragma unroll
    for (int off = 32; off >= 1; off >>= 1) p += __shfl_xor(p, off);
    if (lane == 0) nrm[row] = sqrtf(p);
}

// ---------- 4. sparse attention layer, SINGLE-PASS + fused elu + prev update ----------
// Per edge: wave loads row Wh[j] as float4/lane, butterfly-reduces the dot so
// EVERY lane holds it, then FMAs wval*wj into a per-wave f32x4 accumulator.
// Eliminates the old second gather pass over Wh and the serial n-loop.
__global__ __launch_bounds__(256) void k_spmm(
    const float* __restrict__ Wh, const float* __restrict__ nrm,
    const u16* __restrict__ eidx, const u16* __restrict__ eadjh, const u16* __restrict__ edegh,
    const int* __restrict__ cnt,
    const void* __restrict__ dc, const void* __restrict__ cv, const void* __restrict__ sv,
    float alpha, float* __restrict__ prev, const int* __restrict__ dflag)
{
    const int F = dflag[0];
    __shared__ __align__(16) float whi[NHID];
    __shared__ __align__(16) float red[4][NHID];
    const int i = blockIdx.x, t = threadIdx.x;
    whi[t] = Wh[(size_t)i * NHID + t];
    float e0 = expf(ldsc(cv, 0, F)), e1 = expf(ldsc(cv, 1, F)), e2 = expf(ldsc(cv, 2, F));
    float esum = e0 + e1 + e2;
    float c0 = e0 / esum, c1 = e1 / esum, c2 = e2 / esum;
    float s = softplusf(ldsc(sv, 0, F));
    float d0 = ldsc(dc, 0, F), d1 = ldsc(dc, 1, F);
    float ni = nrm[i];
    int n = cnt[i];
    if (n > ELLW) n = ELLW;
    if (n < 0) n = 0;
    __syncthreads();
    const int lane = t & 63, wvv = t >> 6;
    const float4 wi = *(const float4*)&whi[lane * 4];
    f32x4 acc = {0.f, 0.f, 0.f, 0.f};
    for (int e = wvv; e < n; e += 4) {
        int j = (int)eidx[(size_t)i * ELLW + e] & (NN - 1);
        float4 wj = *(const float4*)&Wh[(size_t)j * NHID + lane * 4];
        float p = wj.x * wi.x + wj.y * wi.y + wj.z * wi.z + wj.w * wi.w;
        #pragma unroll
        for (int off = 32; off >= 1; off >>= 1) p += __shfl_xor(p, off);
        float denom = fmaxf(ni * nrm[j], 1e-9f);
        float ecos = p / denom;
        float sc = softplusf(d0 * u2f(edegh[(size_t)i * ELLW + e]) + d1);
        float att = ecos * u2f(eadjh[(size_t)i * ELLW + e]) * sc;
        float wval = c0 * fmaxf(att, 0.f) + c1 * fminf(att, 0.f);
        acc[0] += wval * wj.x;
        acc[1] += wval * wj.y;
        acc[2] += wval * wj.z;
        acc[3] += wval * wj.w;
    }
    *(f32x4*)&red[wvv][lane * 4] = acc;
    __syncthreads();
    float tot = red[0][t] + red[1][t] + red[2][t] + red[3][t];
    float o = s * (tot + c2 * whi[t]);
    float inner = eluf(o);
    size_t off2 = (size_t)i * NHID + t;
    prev[off2] = alpha * inner + prev[off2];
}

// ---------- 5. small GEMM + fused row norms: Wh2 = prev @ W2^T + b2; nrm2 ----------
__global__ __launch_bounds__(256) void k_gemm16(
    const float* __restrict__ Af, const void* __restrict__ W2p, const void* __restrict__ b2p,
    float* __restrict__ Wh2, float* __restrict__ nrm2, const int* __restrict__ dflag)
{
    const int F = dflag[0];
    __shared__ __align__(16) float Asf[16 * 256];
    __shared__ __align__(16) float Wsf[16 * 256];
    const int t = threadIdx.x;
    const int i0 = blockIdx.x * 16;
    const int sr = t >> 4, soff = (t & 15) * 16;
    #pragma unroll
    for (int q = 0; q < 4; q++)
        *(float4*)&Asf[sr * 256 + soff + q * 4] = *(const float4*)&Af[(size_t)(i0 + sr) * 256 + soff + q * 4];
    if (F) {
        const float* g = (const float*)W2p + (size_t)sr * 256 + soff;
        #pragma unroll
        for (int q = 0; q < 4; q++)
            *(float4*)&Wsf[sr * 256 + soff + q * 4] = ((const float4*)g)[q];
    } else {
        const u16* g = (const u16*)W2p + (size_t)sr * 256 + soff;
        uint4 h0 = ((const uint4*)g)[0];
        uint4 h1 = ((const uint4*)g)[1];
        unsigned int ws8[8] = { h0.x, h0.y, h0.z, h0.w, h1.x, h1.y, h1.z, h1.w };
        #pragma unroll
        for (int q = 0; q < 8; q++) {
            Wsf[sr * 256 + soff + q * 2]     = u2f((u16)(ws8[q] & 0xFFFFu));
            Wsf[sr * 256 + soff + q * 2 + 1] = u2f((u16)(ws8[q] >> 16));
        }
    }
    __syncthreads();
    const int r = t >> 4, c = t & 15;
    float acc = ldsc(b2p, c, F);
    for (int k = 0; k < 256; k++)
        acc += Asf[r * 256 + k] * Wsf[c * 256 + k];
    Wh2[(size_t)(i0 + r) * 16 + c] = acc;
    // fused row norm: lanes with same r are the 16 c's, reduce within 16-lane group
    float ss = acc * acc;
    ss += __shfl_xor(ss, 1); ss += __shfl_xor(ss, 2);
    ss += __shfl_xor(ss, 4); ss += __shfl_xor(ss, 8);
    if (c == 0) nrm2[i0 + r] = sqrtf(ss);
}

// ---------- 6. final layer + log_softmax + softmax + top2 calib (parallel edges) ----------
// 4 waves x 4 groups of 16 lanes = 16 edges in flight; dot + FMA fused per edge.
__global__ __launch_bounds__(256) void k_final(
    const float* __restrict__ Wh2, const float* __restrict__ nrm2,
    const u16* __restrict__ eidx, const u16* __restrict__ eadjh, const u16* __restrict__ edegh,
    const int* __restrict__ cnt,
    const void* __restrict__ dc, const void* __restrict__ cv, const void* __restrict__ sv,
    void* __restrict__ outp, float* __restrict__ calib, const int* __restrict__ dflag)
{
    const int F = dflag[0];
    __shared__ __align__(16) float w2i[16];
    __shared__ __align__(16) float red[4][16];
    __shared__ __align__(16) float lg[16];
    __shared__ float sh_lse;
    const int i = blockIdx.x, t = threadIdx.x;
    const int lane = t & 63, wv = t >> 6;
    const int g = lane >> 4, lc = lane & 15;
    if (t < 16) w2i[t] = Wh2[(size_t)i * 16 + t];
    float e0 = expf(ldsc(cv, 0, F)), e1 = expf(ldsc(cv, 1, F)), e2 = expf(ldsc(cv, 2, F));
    float esum = e0 + e1 + e2;
    float c0 = e0 / esum, c1 = e1 / esum, c2 = e2 / esum;
    float s = softplusf(ldsc(sv, 0, F));
    float d0 = ldsc(dc, 0, F), d1 = ldsc(dc, 1, F);
    float ni = nrm2[i];
    int n = cnt[i];
    if (n > ELLW) n = ELLW;
    if (n < 0) n = 0;
    __syncthreads();
    const float wic = w2i[lc];
    float acc = 0.f;
    const int grp = wv * 4 + g;                 // 0..15
    for (int e = grp; e < n; e += 16) {
        int j = (int)eidx[(size_t)i * ELLW + e] & (NN - 1);
        float vj = Wh2[(size_t)j * 16 + lc];
        float p = vj * wic;
        p += __shfl_xor(p, 1); p += __shfl_xor(p, 2);
        p += __shfl_xor(p, 4); p += __shfl_xor(p, 8);
        float denom = fmaxf(ni * nrm2[j], 1e-9f);
        float sc = softplusf(d0 * u2f(edegh[(size_t)i * ELLW + e]) + d1);
        float att = (p / denom) * u2f(eadjh[(size_t)i * ELLW + e]) * sc;
        float wval = c0 * fmaxf(att, 0.f) + c1 * fminf(att, 0.f);
        acc += wval * vj;
    }
    // cross-group (within wave), then cross-wave reduce
    acc += __shfl_xor(acc, 16);
    acc += __shfl_xor(acc, 32);
    if (lane < 16) red[wv][lane] = acc;
    __syncthreads();
    if (t < 16) {
        float tot = red[0][t] + red[1][t] + red[2][t] + red[3][t];
        lg[t] = s * (tot + c2 * w2i[t]);
    }
    __syncthreads();
    if (t == 0) {
        float m1 = -1e30f, m2 = -1e30f;
        for (int k = 0; k < 16; k++) {
            float v = lg[k];
            if (v > m1) { m2 = m1; m1 = v; } else if (v > m2) m2 = v;
        }
        float sum = 0.f;
        for (int k = 0; k < 16; k++) sum += expf(lg[k] - m1);
        float lse = m1 + logf(sum);
        sh_lse = lse;
        atomicAdd(calib, expf(m1 - lse) + expf(m2 - lse));
    }
    __syncthreads();
    if (t < 16) {
        float lp = lg[t] - sh_lse;
        if (F) {
            float* of = (float*)outp;
            of[(size_t)i * 16 + t] = lp;
            of[131073 + (size_t)i * 16 + t] = expf(lp);
        } else {
            u16* oh = (u16*)outp;
            oh[(size_t)i * 16 + t] = f2b(lp);
            oh[131073 + (size_t)i * 16 + t] = f2b(expf(lp));
        }
    }
}

__global__ void k_calib(const float* __restrict__ calib, void* __restrict__ outp,
                        const int* __restrict__ dflag)
{
    float v = calib[0] * (1.0f / 8192.0f);
    if (dflag[0]) ((float*)outp)[131072] = v;
    else ((u16*)outp)[131072] = f2b(v);
}

extern "C" void kernel_launch(void* const* d_in, const int* in_sizes, int n_in,
                              void* d_out, int out_size, void* d_ws, size_t ws_size,
                              hipStream_t stream)
{
    const void* x     = d_in[0];
    const void* adj   = d_in[1];
    const void* fcn_W = d_in[2];
    const void* fcn_b = d_in[3];
    const void* W0    = d_in[4];
    const void* b0    = d_in[5];
    const void* dc0   = d_in[6];
    const void* c0    = d_in[7];
    const void* s0    = d_in[8];
    const void* W1    = d_in[9];
    const void* b1    = d_in[10];
    const void* dc1   = d_in[11];
    const void* c1    = d_in[12];
    const void* s1    = d_in[13];
    const void* W2    = d_in[14];
    const void* b2    = d_in[15];
    const void* dc2   = d_in[16];
    const void* c2    = d_in[17];
    const void* s2    = d_in[18];

    // workspace layout (~22.6 MB)
    char* w = (char*)d_ws;
    int*   dflag  = (int*)w;    w += 256;
    u16*   eidx   = (u16*)w;    w += (size_t)NN * ELLW * 2;   // 2 MB
    u16*   eadjh  = (u16*)w;    w += (size_t)NN * ELLW * 2;   // 2 MB
    u16*   edegh  = (u16*)w;    w += (size_t)NN * ELLW * 2;   // 2 MB
    int*   cnt    = (int*)w;    w += NN * 4;                  // 32 KB
    float* prev   = (float*)w;  w += (size_t)NN * NHID * 4;   // 8 MB
    float* Wh     = (float*)w;  w += (size_t)NN * NHID * 4;   // 8 MB
    float* nrm    = (float*)w;  w += NN * 4;                  // 32 KB
    float* Wh2    = (float*)w;  w += (size_t)NN * NCLS * 4;   // 512 KB
    float* nrm2   = (float*)w;  w += NN * 4;                  // 32 KB
    float* calib  = (float*)w;  w += 256;

    const float DECAYC = 0.0327898222829908f;  // ln(0.9/27 + 1)

    // 0. dtype probe (bf16 vs fp32 inputs) + calib zero
    k_detect<<<1, 64, 0, stream>>>((const unsigned int*)x, dflag, calib);
    // 1. extract sparsity
    k_extract<<<NN, 256, 0, stream>>>(adj, eidx, eadjh, edegh, cnt, dflag);
    // 2+3. prev = elu(x @ fcn_W^T + fcn_b)  AND  Wh0 = x @ W0^T + b0 (one launch, 256 blocks)
    k_gemm_x<<<dim3(NN / 128, 4), 256, 0, stream>>>(x, fcn_W, fcn_b, W0, b0, prev, Wh, dflag);
    k_rownorm<<<NN / 4, 256, 0, stream>>>(Wh, nrm);
    // 4. layer0 sparse attention + elu + prev += inner (single pass)
    k_spmm<<<NN, 256, 0, stream>>>(Wh, nrm, eidx, eadjh, edegh, cnt, dc0, c0, s0, 1.0f, prev, dflag);
    // 5. Wh1 = prev(f32 split) @ W1^T + b1
    k_gemm<<<dim3(NN / 128, NHID / 128), 256, 0, stream>>>(prev, 1, W1, b1, Wh, NHID, NHID, 1, dflag);
    k_rownorm<<<NN / 4, 256, 0, stream>>>(Wh, nrm);
    // 6. layer1 sparse attention + elu + prev += decay*inner (single pass)
    k_spmm<<<NN, 256, 0, stream>>>(Wh, nrm, eidx, eadjh, edegh, cnt, dc1, c1, s1, DECAYC, prev, dflag);
    // 7. Wh2 = prev(f32) @ W2^T + b2, fused nrm2
    k_gemm16<<<NN / 16, 256, 0, stream>>>(prev, W2, b2, Wh2, nrm2, dflag);
    // 8. final layer + softmaxes + calib
    k_final<<<NN, 256, 0, stream>>>(Wh2, nrm2, eidx, eadjh, edegh, cnt, dc2, c2, s2, d_out, calib, dflag);
    k_calib<<<1, 1, 0, stream>>>(calib, d_out, dflag);
}